// Round 14
// baseline (165.617 us; speedup 1.0000x reference)
//
#include <hip/hip_runtime.h>
#include <math.h>

#define B_ 16
#define S_ 2048
#define IN_DIM 128
#define E2 6
#define E_ 3
#define OUT_DIM 64

// ws layout:
//   [0, 524288)        h as float4 (x,y,z, sq=|h|^2)
//   [524288, 528384)   pmax[1024]  float - per-block max partial
//   [528384, 536576)   pstat[1024] u64   - packed {diag:16|vert:16|total:32}
//   [536576, 536644)   cnt[16] + done    - counters (zeroed by embed)
//
// Lessons: R5/R6 spill; R9/R10 latency-prefetch ~nil; R11 atomics minor;
// R12 threadfence hurt; R13 fused kernel works but grid of 512 blocks caps
// occupancy at 2 waves/SIMD (16.8% measured). R14: 32-row spans -> 1024
// blocks = 4 blocks/CU = 16 waves/CU; embed reverted to 2048-block version.

// one wave per 4 rows: grid 2048 blocks of 256. Block 0 zeroes counters.
__global__ __launch_bounds__(256) void embed_kernel(
    const float* __restrict__ x, const float* __restrict__ w1,
    const float* __restrict__ b1, const float* __restrict__ w2,
    const float* __restrict__ b2, float* __restrict__ hws,
    int* __restrict__ cnt /* cnt[16] then done */)
{
    if (blockIdx.x == 0 && threadIdx.x < 17) cnt[threadIdx.x] = 0;
    int wave = threadIdx.x >> 6;
    int lane = threadIdx.x & 63;
#pragma unroll
    for (int rr = 0; rr < 4; ++rr) {
        int row = blockIdx.x * 16 + wave * 4 + rr;   // [0, B*S)
        const float2* x2 = (const float2*)(x + (size_t)row * IN_DIM);
        float2 xv = x2[lane];
        const float* w1a = w1 + (2 * lane) * E2;     // 12 contiguous floats
        float a[E2];
#pragma unroll
        for (int q = 0; q < E2; ++q)
            a[q] = xv.x * w1a[q] + xv.y * w1a[E2 + q];
#pragma unroll
        for (int q = 0; q < E2; ++q) {
#pragma unroll
            for (int off = 32; off >= 1; off >>= 1)
                a[q] += __shfl_xor(a[q], off, 64);
        }
        if (lane == 0) {
            float r[E2];
#pragma unroll
            for (int q = 0; q < E2; ++q) r[q] = fmaxf(a[q] + b1[q], 0.f);
            float h[E_];
#pragma unroll
            for (int e = 0; e < E_; ++e) {
                float s = b2[e];
#pragma unroll
                for (int q = 0; q < E2; ++q) s += r[q] * w2[q * E_ + e];
                h[e] = s;
            }
            float sq = h[0] * h[0] + h[1] * h[1] + h[2] * h[2];
            ((float4*)hws)[row] = make_float4(h[0], h[1], h[2], sq);
        }
    }
}

// grid: B * 64 rowSpans = 1024 blocks of 256 (4 blocks/CU, 16 waves/CU).
// thread = 8 columns (stride 256); rows r0-1..r0+32 prescaled in LDS once,
// shared by max phase and stats phase. t = sq_r - 2*dot = 3 chained fma.
// Deadlock-free barrier: all 1024 blocks co-resident (256 CU x 4).
__global__ __launch_bounds__(256) void rqa_kernel(
    const float4* __restrict__ h4, const float* __restrict__ theta,
    float* __restrict__ pmax, unsigned long long* __restrict__ pstat,
    int* __restrict__ cnt, int* __restrict__ done,
    const float* __restrict__ w3, const float* __restrict__ b3,
    float* __restrict__ out)
{
    int bid = blockIdx.x;
    int b  = bid >> 6;
    int rb = bid & 63;
    int r0 = rb * 32;
    const float4* hb = h4 + (size_t)b * S_;
    __shared__ float4 sh[34];                    // sh[1+k] = row r0+k, prescaled
    __shared__ float wmax[4];
    __shared__ int wsum[4][2];
    __shared__ int slast;
    if (threadIdx.x < 34) {
        int r = r0 - 1 + threadIdx.x;
        r = r < 0 ? 0 : (r >= S_ ? S_ - 1 : r);
        float4 rv = hb[r];
        sh[threadIdx.x] = make_float4(-2.f * rv.x, -2.f * rv.y, -2.f * rv.z, rv.w);
    }
    float4 hj[8];
#pragma unroll
    for (int c = 0; c < 8; ++c) hj[c] = hb[c * 256 + threadIdx.x];
    __syncthreads();
    int lane = threadIdx.x & 63, wave = threadIdx.x >> 6;

    // ---------------- phase A: max of t over rows sh[1..32] ----------------
    float mc[8];
#pragma unroll
    for (int c = 0; c < 8; ++c) mc[c] = -1e30f;
    {
        float4 rv = sh[32];
#pragma unroll 4
        for (int k = 31; k >= 1; --k) {
            float4 nx = sh[k];                   // prefetch
#pragma unroll
            for (int c = 0; c < 8; ++c) {
                float t = fmaf(hj[c].x, rv.x,
                          fmaf(hj[c].y, rv.y,
                          fmaf(hj[c].z, rv.z, rv.w)));
                mc[c] = fmaxf(mc[c], t);
            }
            rv = nx;
        }
#pragma unroll
        for (int c = 0; c < 8; ++c) {            // final row (rv = sh[1])
            float t = fmaf(hj[c].x, rv.x,
                      fmaf(hj[c].y, rv.y,
                      fmaf(hj[c].z, rv.z, rv.w)));
            mc[c] = fmaxf(mc[c], t);
        }
    }
    float m = -1e30f;
#pragma unroll
    for (int c = 0; c < 8; ++c) m = fmaxf(m, mc[c] + hj[c].w);
    m = fmaxf(m, 0.f);                           // d2 >= 0
#pragma unroll
    for (int off = 32; off >= 1; off >>= 1)
        m = fmaxf(m, __shfl_xor(m, off, 64));
    if (lane == 0) wmax[wave] = m;
    __syncthreads();
    if (threadIdx.x == 0) {
        float mm = fmaxf(fmaxf(wmax[0], wmax[1]), fmaxf(wmax[2], wmax[3]));
        __hip_atomic_store(&pmax[bid], mm, __ATOMIC_RELEASE, __HIP_MEMORY_SCOPE_AGENT);
        __hip_atomic_fetch_add(&cnt[b], 1, __ATOMIC_ACQ_REL, __HIP_MEMORY_SCOPE_AGENT);
        // spin until all 64 blocks of this batch published their max
        while (__hip_atomic_load(&cnt[b], __ATOMIC_ACQUIRE, __HIP_MEMORY_SCOPE_AGENT) < 64)
            __builtin_amdgcn_s_sleep(8);
    }
    __syncthreads();                             // whole block waits on t0's spin

    // reduce the batch's 64 pmax partials (one per lane)
    float pm = __hip_atomic_load(&pmax[b * 64 + lane],
                                 __ATOMIC_RELAXED, __HIP_MEMORY_SCOPE_AGENT);
#pragma unroll
    for (int off = 32; off >= 1; off >>= 1)
        pm = fmaxf(pm, __shfl_xor(pm, off, 64));
    float maxd2 = pm;

    // ---------------- phase B: thresholded stats (R8/R11-verified algebra) --
    float sig   = 1.f / (1.f + expf(-theta[0]));
    float thr2  = sig * sig * maxd2;
    float thrc[8];
#pragma unroll
    for (int c = 0; c < 8; ++c) thrc[c] = thr2 - hj[c].w;  // d2<thr2 <=> t<thrc

    unsigned mk[8];
#pragma unroll
    for (int c = 0; c < 8; ++c) mk[c] = 0u;
    float4 rv = sh[32];                          // row r0+31
#pragma unroll 4
    for (int k = 31; k >= 0; --k) {
        float4 nx = sh[k];                       // at k=0 prefetches sh[0] = prev row
#pragma unroll
        for (int c = 0; c < 8; ++c) {
            float t = fmaf(hj[c].x, rv.x,
                      fmaf(hj[c].y, rv.y,
                      fmaf(hj[c].z, rv.z, rv.w)));
            mk[c] = mk[c] * 2u + ((t < thrc[c]) ? 1u : 0u);  // bit p = row r0+p
        }
        rv = nx;
    }
    float4 pr = rv;                              // sh[0] = row r0-1 (prescaled)
    float4 nxr = sh[33];                         // row r0+32

    int total = 0, diag = 0, vert = 0;
#pragma unroll
    for (int c = 0; c < 8; ++c) {
        int j = c * 256 + threadIdx.x;
        unsigned mm = mk[c];
        total += __popc(mm);
        float tp = fmaf(hj[c].x, pr.x, fmaf(hj[c].y, pr.y, fmaf(hj[c].z, pr.z, pr.w)));
        float tn = fmaf(hj[c].x, nxr.x, fmaf(hj[c].y, nxr.y, fmaf(hj[c].z, nxr.z, nxr.w)));
        unsigned prevbit = (r0 > 0) ? ((tp < thrc[c]) ? 1u : 0u) : 0u;
        unsigned nextbit = (r0 + 32 < S_) ? ((tn < thrc[c]) ? 1u : 0u) : 0u;
        // vertical run starts: R[i] & ~R[i-1] & R[i+1]
        unsigned notprev = ~((mm << 1) | prevbit);
        vert += __popc(mm & notprev & ((mm >> 1) | (nextbit << 31)));
        // diag band: rows s with j-s in [1,9] -> bits [j-9-r0, j-1-r0]
        int lo = j - 9 - r0, hi = j - 1 - r0;
        if (hi >= 0 && lo <= 31) {
            int l = lo < 0 ? 0 : lo;
            int h = hi > 31 ? 31 : hi;
            unsigned bandm = (unsigned)(((1ull << (h - l + 1)) - 1ull) << l);
            diag += __popc(mm & bandm);
        }
    }
    // pack (diag,vert): per-wave diag<=288, vert<=8192 -> fits 16+16
    int dv = (diag << 16) | vert;
#pragma unroll
    for (int off = 32; off >= 1; off >>= 1) {
        total += __shfl_xor(total, off, 64);
        dv    += __shfl_xor(dv,    off, 64);
    }
    if (lane == 0) { wsum[wave][0] = total; wsum[wave][1] = dv; }
    __syncthreads();
    if (threadIdx.x == 0) {
        int t = 0, d = 0, v = 0;
#pragma unroll
        for (int w = 0; w < 4; ++w) {
            t += wsum[w][0];
            d += wsum[w][1] >> 16;
            v += wsum[w][1] & 0xFFFF;
        }
        unsigned long long pk = ((unsigned long long)(unsigned)((d << 16) | v) << 32)
                              | (unsigned long long)(unsigned)t;
        __hip_atomic_store(&pstat[bid], pk, __ATOMIC_RELEASE, __HIP_MEMORY_SCOPE_AGENT);
        int prev = __hip_atomic_fetch_add(done, 1, __ATOMIC_ACQ_REL, __HIP_MEMORY_SCOPE_AGENT);
        slast = (prev == 1023) ? 1 : 0;
    }
    __syncthreads();

    // ---------------- last block finalizes ---------------------------------
    if (slast) {
        __shared__ int stot[16], sdia[16], sver[16];
        int tid = threadIdx.x;
        if (tid < 16) { stot[tid] = 0; sdia[tid] = 0; sver[tid] = 0; }
        __syncthreads();
        for (int i = tid; i < 1024; i += 256) {
            unsigned long long p = __hip_atomic_load(&pstat[i], __ATOMIC_RELAXED,
                                                     __HIP_MEMORY_SCOPE_AGENT);
            int bb = i >> 6;
            atomicAdd(&stot[bb], (int)(p & 0xFFFFFFFFull));
            atomicAdd(&sdia[bb], (int)(p >> 48));
            atomicAdd(&sver[bb], (int)((p >> 32) & 0xFFFFull));
        }
        __syncthreads();
#pragma unroll
        for (int q = 0; q < 4; ++q) {
            int idx = q * 256 + tid;             // 0..1023
            int ob = idx >> 6, o = idx & 63;
            float tt = (float)stot[ob], dd = (float)sdia[ob], vv = (float)sver[ob];
            float rr2  = tt / (float)(S_ * S_);
            float det  = dd / (tt + 1e-6f);
            float lam  = vv / (tt + 1e-6f);
            float entr = -tt * logf(1.0f + 1e-6f);   // fp32 semantics (absmax 0 verified)
            float r = b3[o] + rr2 * w3[0 * OUT_DIM + o]
                            + det * w3[1 * OUT_DIM + o]
                            + lam * w3[2 * OUT_DIM + o]
                            + entr * w3[3 * OUT_DIM + o];
            out[idx] = fmaxf(r, 0.f);
        }
    }
}

extern "C" void kernel_launch(void* const* d_in, const int* in_sizes, int n_in,
                              void* d_out, int out_size, void* d_ws, size_t ws_size,
                              hipStream_t stream) {
    const float* x     = (const float*)d_in[0];
    const float* theta = (const float*)d_in[1];
    const float* w1    = (const float*)d_in[2];
    const float* b1    = (const float*)d_in[3];
    const float* w2    = (const float*)d_in[4];
    const float* b2    = (const float*)d_in[5];
    const float* w3    = (const float*)d_in[6];
    const float* b3    = (const float*)d_in[7];
    float* out = (float*)d_out;
    float* hws = (float*)d_ws;
    float* pmax = (float*)((char*)d_ws + 524288);
    unsigned long long* pstat = (unsigned long long*)((char*)d_ws + 528384);
    int*   cnt  = (int*)((char*)d_ws + 536576);  // cnt[16], then done at [16]
    int*   done = cnt + 16;

    hipLaunchKernelGGL(embed_kernel, dim3(B_ * S_ / 16), dim3(256), 0, stream,
                       x, w1, b1, w2, b2, hws, cnt);
    hipLaunchKernelGGL(rqa_kernel, dim3(B_ * 64), dim3(256), 0, stream,
                       (const float4*)hws, theta, pmax, pstat, cnt, done, w3, b3, out);
}

// Round 15
// 128.571 us; speedup vs baseline: 1.2881x; 1.2881x over previous
//
#include <hip/hip_runtime.h>
#include <math.h>

#define B_ 16
#define S_ 2048
#define IN_DIM 128
#define E2 6
#define E_ 3
#define OUT_DIM 64

// ws layout:
//   [0, 524288)        h as float4 (x,y,z, sq=|h|^2)
//   [524288, 526336)   pmax[512]  float - per-block max partial
//   [526336, 530432)   pstat[512] u64   - packed {diag:16|vert:16|total:32}
//   [530432, 530500)   cnt[16] + done   - counters (zeroed by embed)
//
// Ledger: R5/R6 spill; R9/R10 latency-prefetch ~nil; R11 atomics minor;
// R12 threadfence hurt; R13 fused rqa@512 blocks = 47.7us (GOOD) but embed
// broken (38us); R14 1024-block rqa = 85.8us (occupancy NOT binding; small
// spans lose - twice now). R15: compose R11 embed (2048 blocks, ~5us) with
// R13 rqa verbatim.

// one wave per 4 rows: grid 2048 blocks of 256. Block 0 zeroes counters.
__global__ __launch_bounds__(256) void embed_kernel(
    const float* __restrict__ x, const float* __restrict__ w1,
    const float* __restrict__ b1, const float* __restrict__ w2,
    const float* __restrict__ b2, float* __restrict__ hws,
    int* __restrict__ cnt /* cnt[16] then done */)
{
    if (blockIdx.x == 0 && threadIdx.x < 17) cnt[threadIdx.x] = 0;
    int wave = threadIdx.x >> 6;
    int lane = threadIdx.x & 63;
#pragma unroll
    for (int rr = 0; rr < 4; ++rr) {
        int row = blockIdx.x * 16 + wave * 4 + rr;   // [0, B*S)
        const float2* x2 = (const float2*)(x + (size_t)row * IN_DIM);
        float2 xv = x2[lane];
        const float* w1a = w1 + (2 * lane) * E2;     // 12 contiguous floats
        float a[E2];
#pragma unroll
        for (int q = 0; q < E2; ++q)
            a[q] = xv.x * w1a[q] + xv.y * w1a[E2 + q];
#pragma unroll
        for (int q = 0; q < E2; ++q) {
#pragma unroll
            for (int off = 32; off >= 1; off >>= 1)
                a[q] += __shfl_xor(a[q], off, 64);
        }
        if (lane == 0) {
            float r[E2];
#pragma unroll
            for (int q = 0; q < E2; ++q) r[q] = fmaxf(a[q] + b1[q], 0.f);
            float h[E_];
#pragma unroll
            for (int e = 0; e < E_; ++e) {
                float s = b2[e];
#pragma unroll
                for (int q = 0; q < E2; ++q) s += r[q] * w2[q * E_ + e];
                h[e] = s;
            }
            float sq = h[0] * h[0] + h[1] * h[1] + h[2] * h[2];
            ((float4*)hws)[row] = make_float4(h[0], h[1], h[2], sq);
        }
    }
}

// grid: B * 32 rowSpans = 512 blocks of 256 (R13-measured 47.7us).
// thread = 8 columns (stride 256); rows r0-1..r0+64 prescaled in LDS once,
// shared by max phase and stats phase. t = sq_r - 2*dot = 3 chained fma.
// Deadlock-free barrier: cnt[b] involves only batch b's 32 contiguous blocks.
__global__ __launch_bounds__(256) void rqa_kernel(
    const float4* __restrict__ h4, const float* __restrict__ theta,
    float* __restrict__ pmax, unsigned long long* __restrict__ pstat,
    int* __restrict__ cnt, int* __restrict__ done,
    const float* __restrict__ w3, const float* __restrict__ b3,
    float* __restrict__ out)
{
    int bid = blockIdx.x;
    int b  = bid >> 5;
    int rb = bid & 31;
    int r0 = rb * 64;
    const float4* hb = h4 + (size_t)b * S_;
    __shared__ float4 sh[66];                    // sh[1+k] = row r0+k, prescaled
    __shared__ float wmax[4];
    __shared__ int wsum[4][2];
    __shared__ int slast;
    if (threadIdx.x < 66) {
        int r = r0 - 1 + threadIdx.x;
        r = r < 0 ? 0 : (r >= S_ ? S_ - 1 : r);
        float4 rv = hb[r];
        sh[threadIdx.x] = make_float4(-2.f * rv.x, -2.f * rv.y, -2.f * rv.z, rv.w);
    }
    float4 hj[8];
#pragma unroll
    for (int c = 0; c < 8; ++c) hj[c] = hb[c * 256 + threadIdx.x];
    __syncthreads();
    int lane = threadIdx.x & 63, wave = threadIdx.x >> 6;

    // ---------------- phase A: max of t over rows sh[1..64] ----------------
    float mc[8];
#pragma unroll
    for (int c = 0; c < 8; ++c) mc[c] = -1e30f;
    {
        float4 rv = sh[64];
#pragma unroll 4
        for (int k = 63; k >= 1; --k) {
            float4 nx = sh[k];                   // prefetch
#pragma unroll
            for (int c = 0; c < 8; ++c) {
                float t = fmaf(hj[c].x, rv.x,
                          fmaf(hj[c].y, rv.y,
                          fmaf(hj[c].z, rv.z, rv.w)));
                mc[c] = fmaxf(mc[c], t);
            }
            rv = nx;
        }
#pragma unroll
        for (int c = 0; c < 8; ++c) {            // final row (rv = sh[1])
            float t = fmaf(hj[c].x, rv.x,
                      fmaf(hj[c].y, rv.y,
                      fmaf(hj[c].z, rv.z, rv.w)));
            mc[c] = fmaxf(mc[c], t);
        }
    }
    float m = -1e30f;
#pragma unroll
    for (int c = 0; c < 8; ++c) m = fmaxf(m, mc[c] + hj[c].w);
    m = fmaxf(m, 0.f);                           // d2 >= 0
#pragma unroll
    for (int off = 32; off >= 1; off >>= 1)
        m = fmaxf(m, __shfl_xor(m, off, 64));
    if (lane == 0) wmax[wave] = m;
    __syncthreads();
    if (threadIdx.x == 0) {
        float mm = fmaxf(fmaxf(wmax[0], wmax[1]), fmaxf(wmax[2], wmax[3]));
        __hip_atomic_store(&pmax[bid], mm, __ATOMIC_RELEASE, __HIP_MEMORY_SCOPE_AGENT);
        __hip_atomic_fetch_add(&cnt[b], 1, __ATOMIC_ACQ_REL, __HIP_MEMORY_SCOPE_AGENT);
        // spin until all 32 blocks of this batch published their max
        while (__hip_atomic_load(&cnt[b], __ATOMIC_ACQUIRE, __HIP_MEMORY_SCOPE_AGENT) < 32)
            __builtin_amdgcn_s_sleep(8);
    }
    __syncthreads();                             // whole block waits on t0's spin

    // per-wave reduce of the batch's 32 pmax partials
    float pm = __hip_atomic_load(&pmax[b * 32 + (lane & 31)],
                                 __ATOMIC_RELAXED, __HIP_MEMORY_SCOPE_AGENT);
#pragma unroll
    for (int off = 16; off >= 1; off >>= 1)
        pm = fmaxf(pm, __shfl_xor(pm, off, 64));
    float maxd2 = pm;

    // ---------------- phase B: thresholded stats (verified R11 logic) ------
    float sig   = 1.f / (1.f + expf(-theta[0]));
    float thr2  = sig * sig * maxd2;
    float thrc[8];
#pragma unroll
    for (int c = 0; c < 8; ++c) thrc[c] = thr2 - hj[c].w;  // d2<thr2 <=> t<thrc

    unsigned mlo[8], mhi[8];
#pragma unroll
    for (int c = 0; c < 8; ++c) { mlo[c] = 0u; mhi[c] = 0u; }
    float4 rv = sh[64];                          // row r0+63
#pragma unroll 4
    for (int k = 63; k >= 32; --k) {
        float4 nx = sh[k];
#pragma unroll
        for (int c = 0; c < 8; ++c) {
            float t = fmaf(hj[c].x, rv.x,
                      fmaf(hj[c].y, rv.y,
                      fmaf(hj[c].z, rv.z, rv.w)));
            mhi[c] = mhi[c] * 2u + ((t < thrc[c]) ? 1u : 0u);
        }
        rv = nx;
    }
#pragma unroll 4
    for (int k = 31; k >= 0; --k) {
        float4 nx = sh[k];                       // at k=0 prefetches sh[0] = prev row
#pragma unroll
        for (int c = 0; c < 8; ++c) {
            float t = fmaf(hj[c].x, rv.x,
                      fmaf(hj[c].y, rv.y,
                      fmaf(hj[c].z, rv.z, rv.w)));
            mlo[c] = mlo[c] * 2u + ((t < thrc[c]) ? 1u : 0u);
        }
        rv = nx;
    }
    float4 pr = rv;                              // sh[0] = row r0-1 (prescaled)
    float4 nxr = sh[65];                         // row r0+64

    int total = 0, diag = 0, vert = 0;
#pragma unroll
    for (int c = 0; c < 8; ++c) {
        int j = c * 256 + threadIdx.x;
        unsigned long long mm = ((unsigned long long)mhi[c] << 32) | mlo[c];
        total += __popcll(mm);
        float tp = fmaf(hj[c].x, pr.x, fmaf(hj[c].y, pr.y, fmaf(hj[c].z, pr.z, pr.w)));
        float tn = fmaf(hj[c].x, nxr.x, fmaf(hj[c].y, nxr.y, fmaf(hj[c].z, nxr.z, nxr.w)));
        unsigned long long prevbit = (r0 > 0) ? ((tp < thrc[c]) ? 1ull : 0ull) : 0ull;
        unsigned long long nextbit = (r0 + 64 < S_) ? ((tn < thrc[c]) ? 1ull : 0ull) : 0ull;
        unsigned long long notprev = ~((mm << 1) | prevbit);
        vert += __popcll(mm & notprev & ((mm >> 1) | (nextbit << 63)));
        int lo = j - 9 - r0, hi = j - 1 - r0;
        if (hi >= 0 && lo <= 63) {
            int l = lo < 0 ? 0 : lo;
            int h = hi > 63 ? 63 : hi;
            unsigned long long bandm = ((1ull << (h - l + 1)) - 1ull) << l;
            diag += __popcll(mm & bandm);
        }
    }
    int dv = (diag << 16) | vert;                // diag<=4608, vert<=16384: fits
#pragma unroll
    for (int off = 32; off >= 1; off >>= 1) {
        total += __shfl_xor(total, off, 64);
        dv    += __shfl_xor(dv,    off, 64);
    }
    if (lane == 0) { wsum[wave][0] = total; wsum[wave][1] = dv; }
    __syncthreads();
    if (threadIdx.x == 0) {
        int t = 0, d = 0, v = 0;
#pragma unroll
        for (int w = 0; w < 4; ++w) {
            t += wsum[w][0];
            d += wsum[w][1] >> 16;
            v += wsum[w][1] & 0xFFFF;
        }
        unsigned long long pk = ((unsigned long long)(unsigned)((d << 16) | v) << 32)
                              | (unsigned long long)(unsigned)t;
        __hip_atomic_store(&pstat[bid], pk, __ATOMIC_RELEASE, __HIP_MEMORY_SCOPE_AGENT);
        int prev = __hip_atomic_fetch_add(done, 1, __ATOMIC_ACQ_REL, __HIP_MEMORY_SCOPE_AGENT);
        slast = (prev == 511) ? 1 : 0;
    }
    __syncthreads();

    // ---------------- last block finalizes ---------------------------------
    if (slast) {
        __shared__ int stot[16], sdia[16], sver[16];
        int tid = threadIdx.x;
        if (tid < 16) { stot[tid] = 0; sdia[tid] = 0; sver[tid] = 0; }
        __syncthreads();
        for (int i = tid; i < 512; i += 256) {
            unsigned long long p = __hip_atomic_load(&pstat[i], __ATOMIC_RELAXED,
                                                     __HIP_MEMORY_SCOPE_AGENT);
            int bb = i >> 5;
            atomicAdd(&stot[bb], (int)(p & 0xFFFFFFFFull));
            atomicAdd(&sdia[bb], (int)(p >> 48));
            atomicAdd(&sver[bb], (int)((p >> 32) & 0xFFFFull));
        }
        __syncthreads();
#pragma unroll
        for (int q = 0; q < 4; ++q) {
            int idx = q * 256 + tid;             // 0..1023
            int ob = idx >> 6, o = idx & 63;
            float tt = (float)stot[ob], dd = (float)sdia[ob], vv = (float)sver[ob];
            float rr2  = tt / (float)(S_ * S_);
            float det  = dd / (tt + 1e-6f);
            float lam  = vv / (tt + 1e-6f);
            float entr = -tt * logf(1.0f + 1e-6f);   // fp32 semantics (absmax 0 verified)
            float r = b3[o] + rr2 * w3[0 * OUT_DIM + o]
                            + det * w3[1 * OUT_DIM + o]
                            + lam * w3[2 * OUT_DIM + o]
                            + entr * w3[3 * OUT_DIM + o];
            out[idx] = fmaxf(r, 0.f);
        }
    }
}

extern "C" void kernel_launch(void* const* d_in, const int* in_sizes, int n_in,
                              void* d_out, int out_size, void* d_ws, size_t ws_size,
                              hipStream_t stream) {
    const float* x     = (const float*)d_in[0];
    const float* theta = (const float*)d_in[1];
    const float* w1    = (const float*)d_in[2];
    const float* b1    = (const float*)d_in[3];
    const float* w2    = (const float*)d_in[4];
    const float* b2    = (const float*)d_in[5];
    const float* w3    = (const float*)d_in[6];
    const float* b3    = (const float*)d_in[7];
    float* out = (float*)d_out;
    float* hws = (float*)d_ws;
    float* pmax = (float*)((char*)d_ws + 524288);
    unsigned long long* pstat = (unsigned long long*)((char*)d_ws + 526336);
    int*   cnt  = (int*)((char*)d_ws + 530432);  // cnt[16], then done at [16]
    int*   done = cnt + 16;

    hipLaunchKernelGGL(embed_kernel, dim3(B_ * S_ / 16), dim3(256), 0, stream,
                       x, w1, b1, w2, b2, hws, cnt);
    hipLaunchKernelGGL(rqa_kernel, dim3(B_ * 32), dim3(256), 0, stream,
                       (const float4*)hws, theta, pmax, pstat, cnt, done, w3, b3, out);
}

// Round 16
// 111.768 us; speedup vs baseline: 1.4818x; 1.1503x over previous
//
#include <hip/hip_runtime.h>
#include <math.h>

#define B_ 16
#define S_ 2048
#define IN_DIM 128
#define E2 6
#define E_ 3
#define OUT_DIM 64

// ws layout (atomic-free, R11 structure = measured best 110.8us):
//   [0, 524288)        h as float4 (x,y,z, sq=|h|^2)
//   [524288, 526336)   pmax[512]  float - per-block max partial
//   [526336, 534528)   pstat[512] int4  - per-block {tot,diag,vert,0}
//
// Ledger: R5/R6 spill; R9/R10 latency-prefetch ~nil; R11 best (110.8);
// R12 threadfence hurt; R13-R15 spin-barrier fusion: kernel-local win but
// +18us wall loss -> abandoned. R16 = R11 + upper-triangle prune in max
// (the one clean piece of R12 that was never isolated).

// one wave per 4 rows: grid 2048 blocks of 256.
__global__ __launch_bounds__(256) void embed_kernel(
    const float* __restrict__ x, const float* __restrict__ w1,
    const float* __restrict__ b1, const float* __restrict__ w2,
    const float* __restrict__ b2, float* __restrict__ hws)
{
    int wave = threadIdx.x >> 6;
    int lane = threadIdx.x & 63;
#pragma unroll
    for (int rr = 0; rr < 4; ++rr) {
        int row = blockIdx.x * 16 + wave * 4 + rr;   // [0, B*S)
        const float2* x2 = (const float2*)(x + (size_t)row * IN_DIM);
        float2 xv = x2[lane];
        const float* w1a = w1 + (2 * lane) * E2;     // 12 contiguous floats
        float a[E2];
#pragma unroll
        for (int q = 0; q < E2; ++q)
            a[q] = xv.x * w1a[q] + xv.y * w1a[E2 + q];
#pragma unroll
        for (int q = 0; q < E2; ++q) {
#pragma unroll
            for (int off = 32; off >= 1; off >>= 1)
                a[q] += __shfl_xor(a[q], off, 64);
        }
        if (lane == 0) {
            float r[E2];
#pragma unroll
            for (int q = 0; q < E2; ++q) r[q] = fmaxf(a[q] + b1[q], 0.f);
            float h[E_];
#pragma unroll
            for (int e = 0; e < E_; ++e) {
                float s = b2[e];
#pragma unroll
                for (int q = 0; q < E2; ++q) s += r[q] * w2[q * E_ + e];
                h[e] = s;
            }
            float sq = h[0] * h[0] + h[1] * h[1] + h[2] * h[2];
            ((float4*)hws)[row] = make_float4(h[0], h[1], h[2], sq);
        }
    }
}

// Upper-triangle-pruned max tile: cols [CMIN*256, 2048) vs rows r0..r0+63.
// Coverage: pair (i<=j) handled by block rb=i/64 (its cols include all j>=i:
// for rb>=16, r0>=1024 so chunks 0..3 (cols<1024<=r0) are lower-triangle only).
template<int CMIN>
__device__ __forceinline__ float max_tile(const float4* __restrict__ hb,
                                          const float4* sh, int tid)
{
    float4 hj[8 - CMIN];
#pragma unroll
    for (int c = 0; c < 8 - CMIN; ++c) hj[c] = hb[(c + CMIN) * 256 + tid];
    float mc[8 - CMIN];
#pragma unroll
    for (int c = 0; c < 8 - CMIN; ++c) mc[c] = -1e30f;
    float4 rv = sh[63];
#pragma unroll 4
    for (int k = 62; k >= 0; --k) {
        float4 nx = sh[k];                       // prefetch
#pragma unroll
        for (int c = 0; c < 8 - CMIN; ++c) {
            float t = fmaf(hj[c].x, rv.x,
                      fmaf(hj[c].y, rv.y,
                      fmaf(hj[c].z, rv.z, rv.w)));   // sq_r - 2 dot
            mc[c] = fmaxf(mc[c], t);
        }
        rv = nx;
    }
#pragma unroll
    for (int c = 0; c < 8 - CMIN; ++c) {         // final row (rv = sh[0])
        float t = fmaf(hj[c].x, rv.x,
                  fmaf(hj[c].y, rv.y,
                  fmaf(hj[c].z, rv.z, rv.w)));
        mc[c] = fmaxf(mc[c], t);
    }
    float m = -1e30f;
#pragma unroll
    for (int c = 0; c < 8 - CMIN; ++c) m = fmaxf(m, mc[c] + hj[c].w);
    return m;
}

// grid: B * 32 rowSpans = 512 blocks of 256; rows prescaled (-2x,-2y,-2z,sq).
__global__ __launch_bounds__(256) void max_kernel(
    const float4* __restrict__ h4, float* __restrict__ pmax)
{
    int bid = blockIdx.x;
    int b  = bid >> 5;
    int rb = bid & 31;
    int r0 = rb * 64;
    const float4* hb = h4 + (size_t)b * S_;
    __shared__ float4 sh[64];
    if (threadIdx.x < 64) {
        float4 rv = hb[r0 + threadIdx.x];
        sh[threadIdx.x] = make_float4(-2.f * rv.x, -2.f * rv.y, -2.f * rv.z, rv.w);
    }
    __syncthreads();
    float m = (rb < 16) ? max_tile<0>(hb, sh, threadIdx.x)
                        : max_tile<4>(hb, sh, threadIdx.x);
    m = fmaxf(m, 0.f);                           // d2 >= 0
#pragma unroll
    for (int off = 32; off >= 1; off >>= 1)
        m = fmaxf(m, __shfl_xor(m, off, 64));
    __shared__ float wmax[4];
    int lane = threadIdx.x & 63, wave = threadIdx.x >> 6;
    if (lane == 0) wmax[wave] = m;
    __syncthreads();
    if (threadIdx.x == 0) {
        float mm = fmaxf(fmaxf(wmax[0], wmax[1]), fmaxf(wmax[2], wmax[3]));
        pmax[bid] = mm;                          // plain store - no atomic
    }
}

__global__ __launch_bounds__(256) void stats_kernel(
    const float4* __restrict__ h4, const float* __restrict__ theta,
    const float* __restrict__ pmax, int4* __restrict__ pstat)
{
    int bid = blockIdx.x;
    int b  = bid >> 5;
    int rb = bid & 31;
    int r0 = rb * 64;
    const float4* hb = h4 + (size_t)b * S_;
    __shared__ float4 sh[66];                    // sh[1+k] = row r0+k, prescaled
    if (threadIdx.x < 66) {
        int r = r0 - 1 + threadIdx.x;
        r = r < 0 ? 0 : (r >= S_ ? S_ - 1 : r);
        float4 rv = hb[r];
        sh[threadIdx.x] = make_float4(-2.f * rv.x, -2.f * rv.y, -2.f * rv.z, rv.w);
    }
    float4 hj[8];
#pragma unroll
    for (int c = 0; c < 8; ++c) hj[c] = hb[c * 256 + threadIdx.x];
    __syncthreads();

    // re-reduce this batch's 32 pmax partials in-register (no extra dispatch)
    int lane = threadIdx.x & 63;
    float pm = pmax[b * 32 + (lane & 31)];
#pragma unroll
    for (int off = 16; off >= 1; off >>= 1)
        pm = fmaxf(pm, __shfl_xor(pm, off, 64));
    float maxd2 = pm;

    float sig   = 1.f / (1.f + expf(-theta[0]));
    float thr2  = sig * sig * maxd2;
    float thrc[8];
#pragma unroll
    for (int c = 0; c < 8; ++c) thrc[c] = thr2 - hj[c].w;  // d2<thr2 <=> t<thrc

    // masks built descending: after loop, bit p of (mhi:mlo) = row r0+p
    unsigned mlo[8], mhi[8];
#pragma unroll
    for (int c = 0; c < 8; ++c) { mlo[c] = 0u; mhi[c] = 0u; }

    float4 rv = sh[64];                          // row r0+63
#pragma unroll 4
    for (int k = 63; k >= 32; --k) {
        float4 nx = sh[k];                       // prefetch row r0+k-1
#pragma unroll
        for (int c = 0; c < 8; ++c) {
            float t = fmaf(hj[c].x, rv.x,
                      fmaf(hj[c].y, rv.y,
                      fmaf(hj[c].z, rv.z, rv.w)));
            mhi[c] = mhi[c] * 2u + ((t < thrc[c]) ? 1u : 0u);
        }
        rv = nx;
    }
    // rv = sh[32] = row r0+31
#pragma unroll 4
    for (int k = 31; k >= 0; --k) {
        float4 nx = sh[k];                       // at k=0 prefetches sh[0] = prev row
#pragma unroll
        for (int c = 0; c < 8; ++c) {
            float t = fmaf(hj[c].x, rv.x,
                      fmaf(hj[c].y, rv.y,
                      fmaf(hj[c].z, rv.z, rv.w)));
            mlo[c] = mlo[c] * 2u + ((t < thrc[c]) ? 1u : 0u);
        }
        rv = nx;
    }
    float4 pr = rv;                              // sh[0] = row r0-1 (prescaled)
    float4 nxr = sh[65];                         // row r0+64

    int total = 0, diag = 0, vert = 0;
#pragma unroll
    for (int c = 0; c < 8; ++c) {
        int j = c * 256 + threadIdx.x;
        unsigned long long m = ((unsigned long long)mhi[c] << 32) | mlo[c];
        total += __popcll(m);
        float tp = fmaf(hj[c].x, pr.x, fmaf(hj[c].y, pr.y, fmaf(hj[c].z, pr.z, pr.w)));
        float tn = fmaf(hj[c].x, nxr.x, fmaf(hj[c].y, nxr.y, fmaf(hj[c].z, nxr.z, nxr.w)));
        unsigned long long prevbit = (r0 > 0) ? ((tp < thrc[c]) ? 1ull : 0ull) : 0ull;
        unsigned long long nextbit = (r0 + 64 < S_) ? ((tn < thrc[c]) ? 1ull : 0ull) : 0ull;
        // vertical run starts: R[i] & ~R[i-1] & R[i+1]
        unsigned long long notprev = ~((m << 1) | prevbit);
        vert += __popcll(m & notprev & ((m >> 1) | (nextbit << 63)));
        // diag band: rows s with j-s in [1,9] -> bits [j-9-r0, j-1-r0]
        int lo = j - 9 - r0, hi = j - 1 - r0;
        if (hi >= 0 && lo <= 63) {
            int l = lo < 0 ? 0 : lo;
            int h = hi > 63 ? 63 : hi;
            unsigned long long bandm = ((1ull << (h - l + 1)) - 1ull) << l;
            diag += __popcll(m & bandm);
        }
    }

    // pack (diag,vert) into 16+16 bits: after 64-lane sum diag<=4608, vert<=16384
    int dv = (diag << 16) | vert;
#pragma unroll
    for (int off = 32; off >= 1; off >>= 1) {
        total += __shfl_xor(total, off, 64);
        dv    += __shfl_xor(dv,    off, 64);
    }
    __shared__ int wsum[4][2];
    int wave = threadIdx.x >> 6;
    if (lane == 0) { wsum[wave][0] = total; wsum[wave][1] = dv; }
    __syncthreads();
    if (threadIdx.x == 0) {
        int t = 0, d = 0, v = 0;
#pragma unroll
        for (int w = 0; w < 4; ++w) {
            t += wsum[w][0];
            d += wsum[w][1] >> 16;
            v += wsum[w][1] & 0xFFFF;
        }
        pstat[bid] = make_int4(t, d, v, 0);      // plain store - no atomic
    }
}

// one block of 256 threads: reduce 512 int4 partials, emit 1024 outputs
__global__ __launch_bounds__(256) void finalize_kernel(
    const int4* __restrict__ pstat,
    const float* __restrict__ w3, const float* __restrict__ b3,
    float* __restrict__ out)
{
    __shared__ float stot[16], sdia[16], sver[16];
    int tid = threadIdx.x;
    if (tid < 16) {
        int t = 0, d = 0, v = 0;
        for (int i = 0; i < 32; ++i) {
            int4 p = pstat[tid * 32 + i];
            t += p.x; d += p.y; v += p.z;
        }
        stot[tid] = (float)t; sdia[tid] = (float)d; sver[tid] = (float)v;
    }
    __syncthreads();
#pragma unroll
    for (int q = 0; q < 4; ++q) {
        int idx = q * 256 + tid;                 // 0..1023
        int b = idx >> 6, o = idx & 63;
        float total = stot[b], diag = sdia[b], vert = sver[b];
        float rr  = total / (float)(S_ * S_);
        float det = diag / (total + 1e-6f);
        float lam = vert / (total + 1e-6f);
        float entr = -total * logf(1.0f + 1e-6f);  // fp32 semantics (absmax 0 verified)
        float r = b3[o] + rr  * w3[0 * OUT_DIM + o]
                        + det * w3[1 * OUT_DIM + o]
                        + lam * w3[2 * OUT_DIM + o]
                        + entr * w3[3 * OUT_DIM + o];
        out[idx] = fmaxf(r, 0.f);
    }
}

extern "C" void kernel_launch(void* const* d_in, const int* in_sizes, int n_in,
                              void* d_out, int out_size, void* d_ws, size_t ws_size,
                              hipStream_t stream) {
    const float* x     = (const float*)d_in[0];
    const float* theta = (const float*)d_in[1];
    const float* w1    = (const float*)d_in[2];
    const float* b1    = (const float*)d_in[3];
    const float* w2    = (const float*)d_in[4];
    const float* b2    = (const float*)d_in[5];
    const float* w3    = (const float*)d_in[6];
    const float* b3    = (const float*)d_in[7];
    float* out = (float*)d_out;
    float* hws = (float*)d_ws;
    float* pmax = (float*)((char*)d_ws + 524288);
    int4*  pstat = (int4*)((char*)d_ws + 526336);

    hipLaunchKernelGGL(embed_kernel, dim3(B_ * S_ / 16), dim3(256), 0, stream,
                       x, w1, b1, w2, b2, hws);
    hipLaunchKernelGGL(max_kernel, dim3(B_ * 32), dim3(256), 0, stream,
                       (const float4*)hws, pmax);
    hipLaunchKernelGGL(stats_kernel, dim3(B_ * 32), dim3(256), 0, stream,
                       (const float4*)hws, theta, pmax, pstat);
    hipLaunchKernelGGL(finalize_kernel, dim3(1), dim3(256), 0, stream,
                       pstat, w3, b3, out);
}